// Round 1
// baseline (932.299 us; speedup 1.0000x reference)
//
#include <hip/hip_runtime.h>
#include <math.h>

#define BQ 8
#define SQ 96            // H == W == 96
#define CQ 256
#define OQ 768           // 3*C
#define HWQ 9216         // 96*96
#define PIXQ 73728       // 8*9216

// ---------------------------------------------------------------------------
// Kernel A: QKV projection.  qkv[b,h,w,o] = sum_c x[b,w,h,c]*W[o,c] + bias[o]
// GEMM: M=73728 (pixels, input order p=(b,w,h)), N=768, K=256.
// Tile 128x128, BK=16, 256 threads, 8x8 micro-tile, transposed LDS ([k][row])
// so fragments load as float4 (ds_read_b128).
// ---------------------------------------------------------------------------
__global__ __launch_bounds__(256) void qkv_gemm(
    const float* __restrict__ x, const float* __restrict__ w,
    const float* __restrict__ bias, float* __restrict__ qkv) {
  __shared__ float Als[16][132];   // 132*4B = 528B row, 16B aligned
  __shared__ float Bls[16][132];
  const int tid = threadIdx.x;
  const int tx = tid & 15, ty = tid >> 4;
  const int m0 = blockIdx.x * 128;
  const int n0 = blockIdx.y * 128;
  float acc[8][8] = {};

  for (int k0 = 0; k0 < 256; k0 += 16) {
#pragma unroll
    for (int t = 0; t < 2; ++t) {
      int id = t * 256 + tid;          // 0..511 float4 slots
      int row = id >> 2;               // 0..127
      int kq = (id & 3) * 4;           // 0,4,8,12
      float4 av = *(const float4*)(x + (size_t)(m0 + row) * 256 + k0 + kq);
      Als[kq + 0][row] = av.x; Als[kq + 1][row] = av.y;
      Als[kq + 2][row] = av.z; Als[kq + 3][row] = av.w;
      float4 bv = *(const float4*)(w + (size_t)(n0 + row) * 256 + k0 + kq);
      Bls[kq + 0][row] = bv.x; Bls[kq + 1][row] = bv.y;
      Bls[kq + 2][row] = bv.z; Bls[kq + 3][row] = bv.w;
    }
    __syncthreads();
#pragma unroll
    for (int k = 0; k < 16; ++k) {
      float4 a0 = *(const float4*)&Als[k][ty * 8];
      float4 a1 = *(const float4*)&Als[k][ty * 8 + 4];
      float4 b0 = *(const float4*)&Bls[k][tx * 8];
      float4 b1 = *(const float4*)&Bls[k][tx * 8 + 4];
      float a[8] = {a0.x, a0.y, a0.z, a0.w, a1.x, a1.y, a1.z, a1.w};
      float b[8] = {b0.x, b0.y, b0.z, b0.w, b1.x, b1.y, b1.z, b1.w};
#pragma unroll
      for (int i = 0; i < 8; ++i)
#pragma unroll
        for (int j = 0; j < 8; ++j) acc[i][j] += a[i] * b[j];
    }
    __syncthreads();
  }

  const float4 bias0 = *(const float4*)(bias + n0 + tx * 8);
  const float4 bias1 = *(const float4*)(bias + n0 + tx * 8 + 4);
#pragma unroll
  for (int i = 0; i < 8; ++i) {
    int p = m0 + ty * 8 + i;           // input pixel order (b, w, h)
    int b = p / HWQ;
    int r = p - b * HWQ;
    int ww = r / SQ;
    int hh = r - ww * SQ;
    size_t pout = (size_t)b * HWQ + (size_t)hh * SQ + ww;  // store h-major
    float* dst = qkv + pout * OQ + n0 + tx * 8;
    float4 v0 = make_float4(acc[i][0] + bias0.x, acc[i][1] + bias0.y,
                            acc[i][2] + bias0.z, acc[i][3] + bias0.w);
    float4 v1 = make_float4(acc[i][4] + bias1.x, acc[i][5] + bias1.y,
                            acc[i][6] + bias1.z, acc[i][7] + bias1.w);
    *(float4*)(dst) = v0;
    *(float4*)(dst + 4) = v1;
  }
}

// ---------------------------------------------------------------------------
// Kernel S: attention scores (both), K split across 16 chunks, atomicAdd.
// which=0: Sh[b,h1,h2] = sum_{w,c} q[b,h1,w,c]*k[b,h2,w,c]
// which=1: Sw[b,w1,w2] = sum_{h,c} k[b,h,w1,c]*q[b,h,w2,c]
// qkv layout: [(b*9216 + h*96 + w)*768 + o], q:o<256, k:256+, v:512+
// ---------------------------------------------------------------------------
__global__ __launch_bounds__(256) void attn_scores(
    const float* __restrict__ qkv, float* __restrict__ Sh,
    float* __restrict__ Sw) {
  __shared__ float Xls[96][36];
  __shared__ float Yls[96][36];
  const int tid = threadIdx.x;
  const int tx = tid & 15, ty = tid >> 4;
  const int chunk = blockIdx.x;      // 0..15 (6 kouts each)
  const int b = blockIdx.y;          // 0..7
  const int which = blockIdx.z;      // 0=Sh, 1=Sw
  const size_t base = (size_t)b * HWQ * OQ;
  const int offX = which ? 256 : 0;  // Sh: X=q ; Sw: X=k
  const int offY = which ? 0 : 256;  // Sh: Y=k ; Sw: Y=q
  float acc[6][6] = {};

  for (int it = 0; it < 48; ++it) {
    int kout = chunk * 6 + (it >> 3);   // w (Sh) or h (Sw)
    int c0 = (it & 7) * 32;
#pragma unroll
    for (int t = 0; t < 3; ++t) {
      int id = t * 256 + tid;           // 0..767
      int row = id >> 3;                // 0..95
      int kq = (id & 7) * 4;            // 0..28
      size_t idx = which ? ((size_t)kout * SQ + row) : ((size_t)row * SQ + kout);
      const float* src = qkv + base + idx * OQ + c0 + kq;
      float4 xv = *(const float4*)(src + offX);
      float4 yv = *(const float4*)(src + offY);
      *(float4*)&Xls[row][kq] = xv;     // stride 36 -> 16B aligned
      *(float4*)&Yls[row][kq] = yv;
    }
    __syncthreads();
#pragma unroll
    for (int k2 = 0; k2 < 16; ++k2) {
      int k = k2 * 2;
      float2 a[6], bb[6];
#pragma unroll
      for (int i = 0; i < 6; ++i) a[i] = *(const float2*)&Xls[ty * 6 + i][k];
#pragma unroll
      for (int j = 0; j < 6; ++j) bb[j] = *(const float2*)&Yls[tx * 6 + j][k];
#pragma unroll
      for (int i = 0; i < 6; ++i)
#pragma unroll
        for (int j = 0; j < 6; ++j)
          acc[i][j] += a[i].x * bb[j].x + a[i].y * bb[j].y;
    }
    __syncthreads();
  }
  float* S = which ? Sw : Sh;
#pragma unroll
  for (int i = 0; i < 6; ++i)
#pragma unroll
    for (int j = 0; j < 6; ++j)
      atomicAdd(S + ((size_t)b * SQ + ty * 6 + i) * SQ + tx * 6 + j,
                acc[i][j]);
}

// ---------------------------------------------------------------------------
// Softmax over last dim (96) of Sh (rows 0..767) and Sw (rows 768..1535).
// One wave per row.
// ---------------------------------------------------------------------------
__global__ __launch_bounds__(256) void softmax_rows(float* __restrict__ Sh,
                                                    float* __restrict__ Sw) {
  const int tid = threadIdx.x;
  const int lane = tid & 63;
  const int row = blockIdx.x * 4 + (tid >> 6);
  float* p = (row < 768) ? (Sh + (size_t)row * SQ)
                         : (Sw + (size_t)(row - 768) * SQ);
  float v0 = p[lane];
  float v1 = (lane < 32) ? p[64 + lane] : -3.0e38f;
  float m = fmaxf(v0, v1);
#pragma unroll
  for (int off = 32; off > 0; off >>= 1) m = fmaxf(m, __shfl_xor(m, off));
  float e0 = __expf(v0 - m);
  float e1 = (lane < 32) ? __expf(v1 - m) : 0.0f;
  float s = e0 + e1;
#pragma unroll
  for (int off = 32; off > 0; off >>= 1) s += __shfl_xor(s, off);
  float inv = 1.0f / s;
  p[lane] = e0 * inv;
  if (lane < 32) p[64 + lane] = e1 * inv;
}

// ---------------------------------------------------------------------------
// Kernel D: apply attention.  out layout: ((b*96 + w)*96 + h)*256 + c
// which=0 (per (b, w=xi)): out[b,w,h,c]  = sum_h2 ms[b,h,h2]*V[b,h2,w,c]
// which=1 (per (b, h=xi)): out[b,w,h,c] += sum_w2 ma[b,w,w2]*V[b,h,w2,c]
// GEMM M=96 (rows), N=256 (c), K=96.  256 threads, 6x16 micro-tile.
// ---------------------------------------------------------------------------
__global__ __launch_bounds__(256) void attn_apply(
    const float* __restrict__ qkv, const float* __restrict__ S,
    float* __restrict__ out, const int which) {
  __shared__ float Als[96][100];     // S[b] 96x96, stride 100 (16B aligned)
  __shared__ float Bls[16][256];
  const int tid = threadIdx.x;
  const int tx = tid & 15, ty = tid >> 4;
  const int xi = blockIdx.x;  // w (which=0) or h (which=1)
  const int b = blockIdx.y;

#pragma unroll
  for (int t = 0; t < 9; ++t) {
    int id = t * 256 + tid;          // 0..2303 float4 slots
    int row = id / 24;               // 0..95
    int cq = (id % 24) * 4;          // 0..92
    float4 v = *(const float4*)(S + ((size_t)b * SQ + row) * SQ + cq);
    *(float4*)&Als[row][cq] = v;
  }

  size_t bbase, brs, obase, ors;
  if (which == 0) {
    bbase = ((size_t)b * HWQ + xi) * OQ + 512;          brs = (size_t)SQ * OQ;
    obase = ((size_t)b * HWQ + (size_t)xi * SQ) * CQ;   ors = CQ;
  } else {
    bbase = ((size_t)b * HWQ + (size_t)xi * SQ) * OQ + 512;  brs = OQ;
    obase = ((size_t)b * HWQ + xi) * CQ;                ors = (size_t)SQ * CQ;
  }

  float acc[6][16] = {};
  for (int k0 = 0; k0 < 96; k0 += 16) {
#pragma unroll
    for (int t = 0; t < 4; ++t) {
      int id = t * 256 + tid;        // 0..1023 float4 slots
      int k2 = id >> 6;              // 0..15
      int cq = (id & 63) * 4;        // 0..252
      float4 v = *(const float4*)(qkv + bbase + (size_t)(k0 + k2) * brs + cq);
      *(float4*)&Bls[k2][cq] = v;
    }
    __syncthreads();
#pragma unroll
    for (int k2 = 0; k2 < 16; ++k2) {
      float a[6];
#pragma unroll
      for (int i = 0; i < 6; ++i) a[i] = Als[ty * 6 + i][k0 + k2];
      float4 b0 = *(const float4*)&Bls[k2][tx * 16];
      float4 b1 = *(const float4*)&Bls[k2][tx * 16 + 4];
      float4 b2 = *(const float4*)&Bls[k2][tx * 16 + 8];
      float4 b3 = *(const float4*)&Bls[k2][tx * 16 + 12];
      float bb[16] = {b0.x, b0.y, b0.z, b0.w, b1.x, b1.y, b1.z, b1.w,
                      b2.x, b2.y, b2.z, b2.w, b3.x, b3.y, b3.z, b3.w};
#pragma unroll
      for (int i = 0; i < 6; ++i)
#pragma unroll
        for (int j = 0; j < 16; ++j) acc[i][j] += a[i] * bb[j];
    }
    __syncthreads();
  }

#pragma unroll
  for (int i = 0; i < 6; ++i) {
    int r = ty * 6 + i;
    float* dst = out + obase + (size_t)r * ors + tx * 16;
    if (which == 0) {
#pragma unroll
      for (int q = 0; q < 4; ++q) {
        float4 v = make_float4(acc[i][4 * q + 0], acc[i][4 * q + 1],
                               acc[i][4 * q + 2], acc[i][4 * q + 3]);
        *(float4*)(dst + 4 * q) = v;
      }
    } else {
#pragma unroll
      for (int q = 0; q < 4; ++q) {
        float4 o = *(const float4*)(dst + 4 * q);
        float4 v = make_float4(o.x + acc[i][4 * q + 0], o.y + acc[i][4 * q + 1],
                               o.z + acc[i][4 * q + 2], o.w + acc[i][4 * q + 3]);
        *(float4*)(dst + 4 * q) = v;
      }
    }
  }
}

// ---------------------------------------------------------------------------
extern "C" void kernel_launch(void* const* d_in, const int* in_sizes, int n_in,
                              void* d_out, int out_size, void* d_ws,
                              size_t ws_size, hipStream_t stream) {
  const float* x = (const float*)d_in[0];      // (8,96,96,256)
  const float* w = (const float*)d_in[1];      // (768,256)
  const float* bias = (const float*)d_in[2];   // (768,)
  float* out = (float*)d_out;                  // (8,96,96,256) = (B,W,H,C)

  float* qkv = (float*)d_ws;                          // 56,623,104 floats
  float* Sh = qkv + (size_t)PIXQ * OQ;                // 8*96*96
  float* Sw = Sh + (size_t)BQ * SQ * SQ;              // 8*96*96

  hipMemsetAsync(Sh, 0, 2 * (size_t)BQ * SQ * SQ * sizeof(float), stream);

  qkv_gemm<<<dim3(576, 6), 256, 0, stream>>>(x, w, bias, qkv);
  attn_scores<<<dim3(16, 8, 2), 256, 0, stream>>>(qkv, Sh, Sw);
  softmax_rows<<<dim3(384), 256, 0, stream>>>(Sh, Sw);
  attn_apply<<<dim3(96, 8), 256, 0, stream>>>(qkv, Sh, out, 0);
  attn_apply<<<dim3(96, 8), 256, 0, stream>>>(qkv, Sw, out, 1);
}

// Round 2
// 462.390 us; speedup vs baseline: 2.0163x; 2.0163x over previous
//
#include <hip/hip_runtime.h>
#include <math.h>

#define SQ 96            // H == W == 96
#define CQ 256
#define OQ 768           // 3*C
#define HWQ 9216         // 96*96
#define PIXQ 73728       // 8*9216

typedef __attribute__((ext_vector_type(8))) __bf16 bf16x8;
typedef __attribute__((ext_vector_type(4))) float f32x4;

union FragU { uint4 u; bf16x8 b; };

// round-to-nearest-even fp32 -> bf16 (as u16 in low bits)
__device__ inline uint32_t bf16_rne_u(float f) {
  uint32_t u = __float_as_uint(f);
  return (u + 0x7FFFu + ((u >> 16) & 1u)) >> 16;
}
// split fp32 into hi (RNE bf16) + lo (truncated bf16 of residual), packed u32
__device__ inline uint32_t pack_split(float f) {
  uint32_t hi = bf16_rne_u(f);
  float rem = f - __uint_as_float(hi << 16);
  uint32_t lo = __float_as_uint(rem) >> 16;
  return hi | (lo << 16);
}
// 8 packed u32 (2x uint4) -> hi-frag (8 bf16) and lo-frag (8 bf16)
__device__ inline void unpack_frags(uint4 r0, uint4 r1, FragU& hi, FragU& lo) {
  hi.u.x = (r0.x & 0xFFFFu) | (r0.y << 16);
  hi.u.y = (r0.z & 0xFFFFu) | (r0.w << 16);
  hi.u.z = (r1.x & 0xFFFFu) | (r1.y << 16);
  hi.u.w = (r1.z & 0xFFFFu) | (r1.w << 16);
  lo.u.x = (r0.x >> 16) | (r0.y & 0xFFFF0000u);
  lo.u.y = (r0.z >> 16) | (r0.w & 0xFFFF0000u);
  lo.u.z = (r1.x >> 16) | (r1.y & 0xFFFF0000u);
  lo.u.w = (r1.z >> 16) | (r1.w & 0xFFFF0000u);
}

// ---------------------------------------------------------------------------
// Pack weights: wp[o*256+c] = split(w[o][c])
// ---------------------------------------------------------------------------
__global__ __launch_bounds__(256) void pack_w_kernel(
    const float* __restrict__ w, uint32_t* __restrict__ wp) {
  int i = blockIdx.x * 256 + threadIdx.x;   // 768 blocks x 256 = 196608
  wp[i] = pack_split(w[i]);
}

// ---------------------------------------------------------------------------
// QKV GEMM via split-bf16 MFMA.  M=73728 (p=(b,w,h)), N=768, K=256.
// Block 128x128, 4 waves (2x2) of 64x64, 16x16x32 bf16 MFMA, 4 products.
// Outputs: q,k as packed split-u32 (qk, o<512); v as bf16 (vb).
// Stored h-major: pixel (b,h,w).
// ---------------------------------------------------------------------------
__global__ __launch_bounds__(256) void qkv_gemm_mfma(
    const float* __restrict__ x, const uint32_t* __restrict__ wp,
    const float* __restrict__ bias, uint32_t* __restrict__ qk,
    ushort* __restrict__ vb) {
  __shared__ uint32_t Apk[128 * 32];   // packed hi|lo, [m][k], rows 128B
  __shared__ uint32_t Bpk[128 * 32];   // packed hi|lo, [n][k]
  const int tid = threadIdx.x;
  const int lane = tid & 63;
  const int wid = tid >> 6;
  const int wm = wid >> 1, wn = wid & 1;
  const int lr = lane & 15, quad = lane >> 4;
  const int m0 = blockIdx.x * 128, n0 = blockIdx.y * 128;
  const int sr = tid >> 1, skh = (tid & 1) * 16;   // staging: row, k-half

  f32x4 acc[4][4] = {};

  for (int k0 = 0; k0 < 256; k0 += 32) {
    // stage A (x) with on-the-fly split
    const float* xsrc = x + (size_t)(m0 + sr) * 256 + k0 + skh;
    uint32_t* adst = Apk + sr * 32 + skh;
#pragma unroll
    for (int j = 0; j < 4; ++j) {
      float4 v = *(const float4*)(xsrc + 4 * j);
      uint4 p;
      p.x = pack_split(v.x); p.y = pack_split(v.y);
      p.z = pack_split(v.z); p.w = pack_split(v.w);
      *(uint4*)(adst + 4 * j) = p;
    }
    // stage B (wp, already packed)
    const uint32_t* wsrc = wp + (size_t)(n0 + sr) * 256 + k0 + skh;
    uint32_t* bdst = Bpk + sr * 32 + skh;
#pragma unroll
    for (int j = 0; j < 4; ++j)
      *(uint4*)(bdst + 4 * j) = *(const uint4*)(wsrc + 4 * j);
    __syncthreads();

    FragU ah[4], al[4], bh[4], bl[4];
#pragma unroll
    for (int t = 0; t < 4; ++t) {
      const uint32_t* pa = Apk + (wm * 64 + t * 16 + lr) * 32 + quad * 8;
      unpack_frags(*(const uint4*)pa, *(const uint4*)(pa + 4), ah[t], al[t]);
      const uint32_t* pb = Bpk + (wn * 64 + t * 16 + lr) * 32 + quad * 8;
      unpack_frags(*(const uint4*)pb, *(const uint4*)(pb + 4), bh[t], bl[t]);
    }
#pragma unroll
    for (int i = 0; i < 4; ++i)
#pragma unroll
      for (int j = 0; j < 4; ++j) {
        acc[i][j] = __builtin_amdgcn_mfma_f32_16x16x32_bf16(al[i].b, bl[j].b, acc[i][j], 0, 0, 0);
        acc[i][j] = __builtin_amdgcn_mfma_f32_16x16x32_bf16(al[i].b, bh[j].b, acc[i][j], 0, 0, 0);
        acc[i][j] = __builtin_amdgcn_mfma_f32_16x16x32_bf16(ah[i].b, bl[j].b, acc[i][j], 0, 0, 0);
        acc[i][j] = __builtin_amdgcn_mfma_f32_16x16x32_bf16(ah[i].b, bh[j].b, acc[i][j], 0, 0, 0);
      }
    __syncthreads();
  }

  // epilogue: C[row=(quad*4+r)][col=lr] per 16x16 tile
#pragma unroll
  for (int i = 0; i < 4; ++i) {
    const int growb = m0 + wm * 64 + i * 16 + quad * 4;
#pragma unroll
    for (int r = 0; r < 4; ++r) {
      int p = growb + r;                 // input pixel order (b, w, h)
      int b = p / HWQ;
      int rem = p - b * HWQ;
      int ww = rem / SQ;
      int hh = rem - ww * SQ;
      size_t opix = (size_t)b * HWQ + (size_t)hh * SQ + ww;   // h-major
#pragma unroll
      for (int j = 0; j < 4; ++j) {
        int o = n0 + wn * 64 + j * 16 + lr;
        float val = acc[i][j][r] + bias[o];
        if (o < 512) qk[opix * 512 + o] = pack_split(val);
        else vb[opix * 256 + (o - 512)] = (ushort)bf16_rne_u(val);
      }
    }
  }
}

// ---------------------------------------------------------------------------
// Attention scores via split-bf16 MFMA, K split across 32 chunks, atomicAdd.
// which=0: Sh[b,h1,h2] = sum_{w,c} q[b,h1,w,c]*k[b,h2,w,c]
// which=1: Sw[b,w1,w2] = sum_{h,c} k[b,h,w1,c]*q[b,h,w2,c]
// qk layout: [(b*9216 + h*96 + w)*512 + o] packed u32, q:o<256, k:256+.
// Block: M=96,N=96, 4 waves (2x2) of 48x48, K=3 kouts x 256c = 768.
// ---------------------------------------------------------------------------
__global__ __launch_bounds__(256) void attn_scores_mfma(
    const uint32_t* __restrict__ qk, float* __restrict__ Sh,
    float* __restrict__ Sw) {
  __shared__ uint32_t Xpk[96 * 32];
  __shared__ uint32_t Ypk[96 * 32];
  const int tid = threadIdx.x;
  const int lane = tid & 63;
  const int wid = tid >> 6;
  const int wm = wid >> 1, wn = wid & 1;
  const int lr = lane & 15, quad = lane >> 4;
  const int chunk = blockIdx.x;      // 0..31 (3 kouts each)
  const int b = blockIdx.y;          // 0..7
  const int which = blockIdx.z;      // 0=Sh, 1=Sw
  const size_t base = (size_t)b * HWQ * 512;
  const int offX = which ? 256 : 0;
  const int offY = which ? 0 : 256;

  f32x4 acc[3][3] = {};

  for (int it = 0; it < 24; ++it) {
    int kout = chunk * 3 + (it >> 3);     // w (Sh) or h (Sw)
    int c0 = (it & 7) * 32;
#pragma unroll
    for (int j = 0; j < 3; ++j) {
      int s = j * 256 + tid;              // 0..767 uint4 slots
      int row = s >> 3;                   // 0..95
      int c4 = (s & 7) * 4;
      size_t idx = which ? ((size_t)kout * SQ + row) : ((size_t)row * SQ + kout);
      const uint32_t* src = qk + base + idx * 512 + c0 + c4;
      *(uint4*)(Xpk + row * 32 + c4) = *(const uint4*)(src + offX);
      *(uint4*)(Ypk + row * 32 + c4) = *(const uint4*)(src + offY);
    }
    __syncthreads();
    FragU xh[3], xl[3], yh[3], yl[3];
#pragma unroll
    for (int t = 0; t < 3; ++t) {
      const uint32_t* px = Xpk + (wm * 48 + t * 16 + lr) * 32 + quad * 8;
      unpack_frags(*(const uint4*)px, *(const uint4*)(px + 4), xh[t], xl[t]);
      const uint32_t* py = Ypk + (wn * 48 + t * 16 + lr) * 32 + quad * 8;
      unpack_frags(*(const uint4*)py, *(const uint4*)(py + 4), yh[t], yl[t]);
    }
#pragma unroll
    for (int i = 0; i < 3; ++i)
#pragma unroll
      for (int j = 0; j < 3; ++j) {
        acc[i][j] = __builtin_amdgcn_mfma_f32_16x16x32_bf16(xl[i].b, yl[j].b, acc[i][j], 0, 0, 0);
        acc[i][j] = __builtin_amdgcn_mfma_f32_16x16x32_bf16(xl[i].b, yh[j].b, acc[i][j], 0, 0, 0);
        acc[i][j] = __builtin_amdgcn_mfma_f32_16x16x32_bf16(xh[i].b, yl[j].b, acc[i][j], 0, 0, 0);
        acc[i][j] = __builtin_amdgcn_mfma_f32_16x16x32_bf16(xh[i].b, yh[j].b, acc[i][j], 0, 0, 0);
      }
    __syncthreads();
  }
  float* S = which ? Sw : Sh;
#pragma unroll
  for (int i = 0; i < 3; ++i)
#pragma unroll
    for (int r = 0; r < 4; ++r)
#pragma unroll
      for (int j = 0; j < 3; ++j) {
        int row = wm * 48 + i * 16 + quad * 4 + r;
        int col = wn * 48 + j * 16 + lr;
        atomicAdd(S + ((size_t)b * SQ + row) * SQ + col, acc[i][j][r]);
      }
}

// ---------------------------------------------------------------------------
// Softmax over last dim (96); emits bf16 probabilities.
// rows 0..767 -> Sh -> Pms ; rows 768..1535 -> Sw -> Pma
// ---------------------------------------------------------------------------
__global__ __launch_bounds__(256) void softmax_p(
    const float* __restrict__ Sh, const float* __restrict__ Sw,
    ushort* __restrict__ Pms, ushort* __restrict__ Pma) {
  const int tid = threadIdx.x;
  const int lane = tid & 63;
  const int row = blockIdx.x * 4 + (tid >> 6);
  const float* p = (row < 768) ? (Sh + (size_t)row * SQ)
                               : (Sw + (size_t)(row - 768) * SQ);
  ushort* q = (row < 768) ? (Pms + (size_t)row * SQ)
                          : (Pma + (size_t)(row - 768) * SQ);
  float v0 = p[lane];
  float v1 = (lane < 32) ? p[64 + lane] : -3.0e38f;
  float m = fmaxf(v0, v1);
#pragma unroll
  for (int off = 32; off > 0; off >>= 1) m = fmaxf(m, __shfl_xor(m, off));
  float e0 = __expf(v0 - m);
  float e1 = (lane < 32) ? __expf(v1 - m) : 0.0f;
  float s = e0 + e1;
#pragma unroll
  for (int off = 32; off > 0; off >>= 1) s += __shfl_xor(s, off);
  float inv = 1.0f / s;
  q[lane] = (ushort)bf16_rne_u(e0 * inv);
  if (lane < 32) q[64 + lane] = (ushort)bf16_rne_u(e1 * inv);
}

// ---------------------------------------------------------------------------
// Apply attention via single-bf16 MFMA.  out: ((b*96 + w)*96 + h)*256 + c
// which=0 (block b, xi=w): O[h][c]  = sum_h2 Pms[b,h,h2] * V[b,h2,xi,c]
// which=1 (block b, xi=h): O[w][c] += sum_w2 Pma[b,w,w2] * V[b,xi,w2,c]
// M=96, N=256, K=96.  4 waves (2x2) of 48x128.  V transposed into LDS [c][k].
// ---------------------------------------------------------------------------
__global__ __launch_bounds__(256) void attn_apply_mfma(
    const ushort* __restrict__ vb, const ushort* __restrict__ P,
    float* __restrict__ out, const int which) {
  __shared__ ushort Vt[256 * 40];      // [c][k] stride 40 (80B, 16B-mult)
  const int tid = threadIdx.x;
  const int lane = tid & 63;
  const int wid = tid >> 6;
  const int wm = wid >> 1, wn = wid & 1;
  const int lr = lane & 15, quad = lane >> 4;
  const int xi = blockIdx.x;           // w (which=0) or h (which=1)
  const int b = blockIdx.y;

  f32x4 acc[3][8] = {};

  for (int k0 = 0; k0 < 96; k0 += 32) {
    // stage V-tile (32 k x 256 c) transposed via 2x2 micro-blocks
#pragma unroll
    for (int j = 0; j < 8; ++j) {
      int bi = j * 256 + tid;          // 0..2047
      int c2 = bi & 127;               // c-pair index
      int k2 = bi >> 7;                // k-pair index 0..15
      int k = k0 + k2 * 2;
      int c = c2 * 2;
      size_t r0, r1;
      if (which == 0) {
        r0 = ((size_t)b * HWQ + (size_t)k * SQ + xi) * CQ + c;
        r1 = r0 + (size_t)SQ * CQ;
      } else {
        r0 = ((size_t)b * HWQ + (size_t)xi * SQ + k) * CQ + c;
        r1 = r0 + CQ;
      }
      uint32_t a0 = *(const uint32_t*)(vb + r0);       // V[k][c], V[k][c+1]
      uint32_t a1 = *(const uint32_t*)(vb + r1);       // V[k+1][c], V[k+1][c+1]
      uint32_t w0 = (a0 & 0xFFFFu) | (a1 << 16);       // Vt[c][k..k+1]
      uint32_t w1 = (a0 >> 16) | (a1 & 0xFFFF0000u);   // Vt[c+1][k..k+1]
      *(uint32_t*)&Vt[c * 40 + k2 * 2] = w0;
      *(uint32_t*)&Vt[(c + 1) * 40 + k2 * 2] = w1;
    }
    __syncthreads();
    // A frags straight from global P (L1/L2-hot, reused by 96 blocks)
    FragU a[3];
#pragma unroll
    for (int t = 0; t < 3; ++t) {
      int row = wm * 48 + t * 16 + lr;
      const ushort* ps = P + ((size_t)b * SQ + row) * SQ + k0 + quad * 8;
      a[t].u = *(const uint4*)ps;
    }
#pragma unroll
    for (int j = 0; j < 8; ++j) {
      int cb = wn * 128 + j * 16 + lr;
      FragU bf;
      bf.u = *(const uint4*)&Vt[cb * 40 + quad * 8];
#pragma unroll
      for (int i = 0; i < 3; ++i)
        acc[i][j] = __builtin_amdgcn_mfma_f32_16x16x32_bf16(a[i].b, bf.b, acc[i][j], 0, 0, 0);
    }
    __syncthreads();
  }

#pragma unroll
  for (int i = 0; i < 3; ++i) {
#pragma unroll
    for (int r = 0; r < 4; ++r) {
      int mrow = wm * 48 + i * 16 + quad * 4 + r;
      size_t obase;
      if (which == 0) obase = (((size_t)b * SQ + xi) * SQ + mrow) * CQ;
      else            obase = (((size_t)b * SQ + mrow) * SQ + xi) * CQ;
#pragma unroll
      for (int j = 0; j < 8; ++j) {
        int c = wn * 128 + j * 16 + lr;
        if (which == 0) out[obase + c] = acc[i][j][r];
        else            out[obase + c] += acc[i][j][r];
      }
    }
  }
}

// ---------------------------------------------------------------------------
extern "C" void kernel_launch(void* const* d_in, const int* in_sizes, int n_in,
                              void* d_out, int out_size, void* d_ws,
                              size_t ws_size, hipStream_t stream) {
  const float* x = (const float*)d_in[0];      // (8,96,96,256) = (B,W,H,C)
  const float* w = (const float*)d_in[1];      // (768,256)
  const float* bias = (const float*)d_in[2];   // (768,)
  float* out = (float*)d_out;                  // (8,96,96,256) = (B,W,H,C)

  // workspace layout (~190 MB)
  uint32_t* qk  = (uint32_t*)d_ws;                       // 73728*512 u32
  ushort*   vb  = (ushort*)(qk + (size_t)PIXQ * 512);    // 73728*256 ushort
  float*    Sh  = (float*)(vb + (size_t)PIXQ * 256);     // 73728 f32
  float*    Sw  = Sh + PIXQ;                             // 73728 f32
  ushort*   Pms = (ushort*)(Sw + PIXQ);                  // 73728 ushort
  ushort*   Pma = Pms + PIXQ;                            // 73728 ushort
  uint32_t* wp  = (uint32_t*)(Pma + PIXQ);               // 196608 u32

  hipMemsetAsync(Sh, 0, 2 * (size_t)PIXQ * sizeof(float), stream);

  pack_w_kernel<<<dim3(768), 256, 0, stream>>>(w, wp);
  qkv_gemm_mfma<<<dim3(576, 6), 256, 0, stream>>>(x, wp, bias, qk, vb);
  attn_scores_mfma<<<dim3(32, 8, 2), 256, 0, stream>>>(qk, Sh, Sw);
  softmax_p<<<dim3(384), 256, 0, stream>>>(Sh, Sw, Pms, Pma);
  attn_apply_mfma<<<dim3(96, 8), 256, 0, stream>>>(vb, Pms, out, 0);
  attn_apply_mfma<<<dim3(96, 8), 256, 0, stream>>>(vb, Pma, out, 1);
}